// Round 12
// baseline (371.423 us; speedup 1.0000x reference)
//
#include <hip/hip_runtime.h>
#include <math.h>

// Problem constants: y is (8, 3, 256, 512) fp32, lmbd is (1,3).
#define TVW 512      // row length
#define TVH 256      // H (for channel index)
#define TVC 3        // channels
#define WPB 2        // waves (= rows) per block; 3072 blocks -> 12 blk/CU, 24 waves/CU
#define BLOCK (WPB * 64)
#define PADF 128     // pad floats: max window read = 510+56+63 = 629 < 512+128

// v14 = v13 (register-window broadcast, readlane extracts, no bneg/rtab,
// decoupled waves; 192.9us) + BRANCHLESS GROUPS OF 4. r10/r11 falsified
// SALU-bound and LDS-bound; counter arithmetic: per-absorb wave-time ~120cy
// vs ~17cy VALU issue -> the per-step ballot->s_cbranch serialization
// (~2500/row) is the dominant stall. Fix: absorb 4 elements with NO branch,
// tracking fm = min(u_t); ONE ballot/branch per group. On fire: restore a
// 6-reg snapshot (u,v,kmv,kcv) and replay the 4 steps with the branchy
// TVSTEP -- identical arithmetic (same windows, rcp-window reciprocals used
// everywhere now), so the fire re-occurs and routes to the unchanged
// handlers. Post-fire garbage steps in a group are benign (no overflow,
// discarded by restore). Slides happen pre-snapshot so replay stays
// in-window. Mean fire-free run ~16 absorbs -> ~3 clean groups per event.
__global__ __launch_bounds__(BLOCK)
void tv1d_condat_wave_kernel(const float* __restrict__ y,
                             const float* __restrict__ lmbd,
                             float* __restrict__ out,
                             int total_rows) {
    __shared__ __align__(16) float buf[WPB * TVW + PADF];
    const int tid  = threadIdx.x;
    const int wave = tid >> 6;
    const int lane = tid & 63;
    const int l32  = lane & 31;
    const bool hi  = lane >= 32;
    const int row  = blockIdx.x * WPB + wave;

// uniform float extract: v_readlane (lane index SGPR or inline const)
#define RLF(SRC, IDX) __uint_as_float(__builtin_amdgcn_readlane(__float_as_uint(SRC), (IDX)))

    if (row < total_rows) {
        // ---- per-wave staging: own row only (coalesced float4) ----
        {
            const float4* s4 = (const float4*)(y + (size_t)row * TVW);
            float4* b4 = (float4*)(buf + wave * TVW);
            #pragma unroll
            for (int i = 0; i < TVW / 4; i += 64)
                b4[i + lane] = s4[i + lane];
        }

        const int c = (row / TVH) % TVC;
        float lam = log1pf(expf(lmbd[c]));   // softplus, once per row
        lam = __uint_as_float(__builtin_amdgcn_readfirstlane(__float_as_uint(lam)));
        const float nlam   = -lam;
        const float twolam = 2.0f * lam;
        float* x = buf + wave * TVW;         // row; prefix [..k0) never re-read

        const float sgn   = hi ? -1.0f : 1.0f;     // hi runs the mirrored walk
        const float vnlam = -lam;                  // fma addend
        const float vmcn  = hi ? -twolam : -0.0f;  // -(cneg): neg-jump restart
        const float vmcp  = hi ? -0.0f : -twolam;  // -(cpos): pos-jump restart
        const float laneF = (float)lane;
        const float rw0c  = __builtin_amdgcn_rcpf(laneF + 1.0f);   // den window 0
        const float rw1c  = __builtin_amdgcn_rcpf(laneF + 57.0f);  // den window 1

        // All cross-label state declared up-front (goto-safe).
        int k0, wb, trips, trips_rel, s_ji, seg_guard, kmv, kcv;
        int kms, kcs, rp_end;
        unsigned long long jb;
        float u, v, nvs, wv, tt, denbF, rwin, rwin2, ywin, ywin2;
        float us, vs, fm;
        bool negj;

        // Packed walk state: lo lanes = (umin,vmin); hi lanes = (-umax,-vmax).
        k0 = 0; seg_guard = 4096; jb = 0;
        ywin  = x[lane];                 // window: ywin[lane i] = x[wb + i]
        ywin2 = x[56 + lane];
        nvs = RLF(ywin, 0);              // x[0]
        v = fmaf(sgn, nvs, vnlam);       // lo: y0-lam ; hi: -(y0+lam)
        u = lam;
        kmv = 0; kcv = 1;

// branchy absorb (replay / remainder): SY = uniform raw y, SR = 1/den
#define TVSTEP(SY, SR) { \
            const float u_t = fmaf(sgn, (SY), u) - v; \
            jb = __ballot(u_t < nlam);   /* lo: umin_t<-lam, hi: umax_t>lam */ \
            if (jb) goto midjump; \
            kmv = (u_t >= lam) ? kcv : kmv;  /* v_cmp + v_cndmask */ \
            kcv += 1; \
            const float u_n = fminf(u_t, lam); \
            v = fmaf(u_t - u_n, (SR), v);    /* both clamp corrections */ \
            u = u_n; }

// branchless absorb: accumulate fire evidence into fm (min of u_t)
#define TVSTEP_NB(SY, SR) { \
            const float u_t = fmaf(sgn, (SY), u) - v; \
            fm = fminf(fm, u_t); \
            kmv = (u_t >= lam) ? kcv : kmv; \
            kcv += 1; \
            const float u_n = fminf(u_t, lam); \
            v = fmaf(u_t - u_n, (SR), v); \
            u = u_n; }

// rotate windows forward by 56 elements (uniform)
#define TVSLIDE() { \
            ywin = ywin2; \
            wb += 56; \
            ywin2 = x[wb + 56 + lane]; \
            s_ji -= 56; trips_rel -= 56; \
            rwin = rwin2; \
            rwin2 = __builtin_amdgcn_rcpf(laneF + denbF); \
            denbF += 56.0f; }

seg_start:
        if (--seg_guard < 0) goto done;      // safety; k0 strictly increases
        trips = (TVW - 1) - k0;
        trips_rel = trips;
        wb = k0;
        s_ji = 1;                            // element k0+d at ywin idx d-56s
        denbF = 113.0f;                      // den base for slide s=2
        rwin = rw0c; rwin2 = rw1c;
group_loop:
        for (;;) {
            if (s_ji + 3 > trips_rel) break; // remainder -> singles
            if (s_ji > 60) TVSLIDE()         // group reads idx <= s_ji+3 <= 63
            us = u; vs = v; kms = kmv; kcs = kcv;   // snapshot
            fm = 1.0e30f;
            {
                const int j0 = s_ji, j1 = s_ji + 1, j2 = s_ji + 2, j3 = s_ji + 3;
                const float y0 = RLF(ywin, j0), y1 = RLF(ywin, j1),
                            y2 = RLF(ywin, j2), y3 = RLF(ywin, j3);
                const float r0 = RLF(rwin, j0), r1 = RLF(rwin, j1),
                            r2 = RLF(rwin, j2), r3 = RLF(rwin, j3);
                TVSTEP_NB(y0, r0) TVSTEP_NB(y1, r1)
                TVSTEP_NB(y2, r2) TVSTEP_NB(y3, r3)
            }
            jb = __ballot(fm < nlam);        // ONE fire test per 4 absorbs
            if (jb) {                        // fire somewhere in the group:
                u = us; v = vs; kmv = kms; kcv = kcs;   // restore snapshot
                rp_end = s_ji + 4;
                goto replay;
            }
            s_ji += 4;
        }
        // ---- singles remainder (<=3) ----
        while (s_ji <= trips_rel) {
            if (s_ji > 63) TVSLIDE()
            TVSTEP(RLF(ywin, s_ji), RLF(rwin, s_ji))
            s_ji += 1;
        }
        goto boundary;

replay: // re-run [s_ji, rp_end) branchy; identical arithmetic -> fire recurs
        while (s_ji < rp_end) {
            TVSTEP(RLF(ywin, s_ji), RLF(rwin, s_ji))
            s_ji += 1;
        }
        goto group_loop;                     // (unreachable in practice)

boundary: // k == W-1 absorbed; u = umin (lo) / -umax (hi)
        {
            const unsigned long long bb = __ballot(u < 0.0f); // lo: umin<0, hi: umax>0
            if ((unsigned)bb) {              // flush [k0..km] at vmin; keep vmax/kp
                const int fe = __builtin_amdgcn_readlane(kmv, 0);   // km
                const int k0n = fe + 1;
                wv = v;                      // lo lanes hold vmin natively
                if (k0n < TVW) {             // window reload issued before stores
                    ywin  = x[k0n + lane];
                    ywin2 = x[k0n + 56 + lane];
                }
                { const int pe = fe < TVW - 1 ? fe : TVW - 1;
                  if (!hi) for (int p = k0 + l32; p <= pe; p += 32) x[p] = wv; }
                if (k0n >= TVW) goto done;
                nvs = RLF(ywin, 0);          // x[k0n]
                tt = fmaf(sgn, nvs, vnlam);  // hi: -x[k0n]-lam (lo value unused)
                u = hi ? (tt - v) : lam;     // uses OLD v (V_old)
                v = hi ? v : nvs;
                kmv = hi ? kmv : k0n;        // reset km (lo) only; kp kept
                kcv = k0n + 1;
                k0 = k0n;
                goto seg_start;
            } else if ((unsigned)(bb >> 32)) { // flush [k0..kp] at vmax; keep vmin/km
                const int fe = __builtin_amdgcn_readlane(kmv, 32);  // kp
                const int k0n = fe + 1;
                wv = -v;                     // hi lanes hold -vmax natively
                if (k0n < TVW) {
                    ywin  = x[k0n + lane];
                    ywin2 = x[k0n + 56 + lane];
                }
                { const int pe = fe < TVW - 1 ? fe : TVW - 1;
                  if (hi) for (int p = k0 + l32; p <= pe; p += 32) x[p] = wv; }
                if (k0n >= TVW) goto done;
                nvs = RLF(ywin, 0);
                tt = nvs + vnlam;            // lo: x[k0n]-lam (hi value unused)
                u = hi ? lam : (tt - v);     // uses OLD v (vmin)
                v = hi ? (-nvs) : v;
                kmv = hi ? k0n : kmv;        // reset kp (hi) only; km kept
                kcv = k0n + 1;
                k0 = k0n;
                goto seg_start;
            } else {                         // terminate: flush tail at mean value
                const float vt = fmaf(u, __builtin_amdgcn_rcpf((float)(trips + 1)), v);
                if (!hi) for (int p = k0 + l32; p < TVW; p += 32) x[p] = vt;
                goto done;
            }
        }

midjump: // jump while absorbing; jb lo bits = negative (priority), hi = positive
        {
            negj = (unsigned)jb != 0;
            const int fe = __builtin_amdgcn_readlane(kmv, negj ? 0 : 32); // km or kp
            const int k0n = fe + 1;          // fe <= W-2 here
            wv = hi ? -v : v;                // value this half would write
            ywin  = x[k0n + lane];           // reload issued before the stores
            ywin2 = x[k0n + 56 + lane];
            {
                const int p0 = k0 + l32;
                if ((negj != hi) && (p0 <= fe)) x[p0] = wv;   // common case: 1 store
                if (fe - k0 >= 32) {                          // rare long segment
                    if (negj != hi)
                        for (int p = p0 + 32; p <= fe; p += 32) x[p] = wv;
                }
            }
            nvs = RLF(ywin, 0);              // x[k0n]
            v = fmaf(sgn, nvs, negj ? vmcn : vmcp);  // restart algebra, sign-folded
            u = lam;
            kmv = k0n; kcv = k0n + 1;
            k0 = k0n;
            goto seg_start;
        }
#undef TVSTEP
#undef TVSTEP_NB
#undef TVSLIDE
done:   ;
        // ---- per-wave coalesced float4 writeback LDS -> out ----
        {
            const float4* b4 = (const float4*)(buf + wave * TVW);
            float4* d4 = (float4*)(out + (size_t)row * TVW);
            #pragma unroll
            for (int i = 0; i < TVW / 4; i += 64)
                d4[i + lane] = b4[i + lane];
        }
    }
#undef RLF
}

extern "C" void kernel_launch(void* const* d_in, const int* in_sizes, int n_in,
                              void* d_out, int out_size, void* d_ws, size_t ws_size,
                              hipStream_t stream) {
    const float* y    = (const float*)d_in[0];
    const float* lmbd = (const float*)d_in[1];
    float* out = (float*)d_out;

    const int total_rows = in_sizes[0] / TVW;              // 6144
    const int grid = (total_rows + WPB - 1) / WPB;         // 3072 blocks
    tv1d_condat_wave_kernel<<<grid, BLOCK, 0, stream>>>(y, lmbd, out, total_rows);
}

// Round 13
// 331.449 us; speedup vs baseline: 1.1206x; 1.1206x over previous
//
#include <hip/hip_runtime.h>
#include <math.h>

// Problem constants: y is (8, 3, 256, 512) fp32, lmbd is (1,3).
#define TVW 512      // row length
#define TVH 256      // H (for channel index)
#define TVC 3        // channels
#define WPB 2        // waves (= rows) per block; 3072 blocks -> 12 blk/CU, 24 waves/CU
#define BLOCK (WPB * 64)
#define PADF 128     // pad: max window read = wb(<=511)+56+63 = 630 < 512+128

// v15 = v13 (register-window broadcast, readlane extracts, half-wave fusion,
// decoupled waves; 192.9us) + PERSISTENT WINDOWS. r12 established events fire
// every ~4 absorbs (~600/row) and that VALU has headroom (82% busy reachable).
// The untouched constant since v9: every event handler reloads the y-window
// and immediately consumes it -> ~120cy serial LDS round trip x 600 events
// ~= 66K of ~306K cy/row. Fix: windows persist across events (invariant
// wb <= k0); handlers take nvs = readlane(ywin, k0n-wb) -- register-only
// restart. Slides (+56) happen only when k0n-wb >= 56 (~9/row), consuming
// data loaded >=56 absorbs earlier -> latency hidden. Hot loop A (j<=63)
// uses constant recip window rwc[rd]=rcp(rd+1) (rd<=j<=63 provable); loop B
// (j in [64,jend]) reads ywin2 with amortized slide + inline rcpf (v14
// proved rcp-everywhere passes). Decisions/flush algebra identical to v13.
__global__ __launch_bounds__(BLOCK)
void tv1d_condat_wave_kernel(const float* __restrict__ y,
                             const float* __restrict__ lmbd,
                             float* __restrict__ out,
                             int total_rows) {
    __shared__ __align__(16) float buf[WPB * TVW + PADF];
    const int tid  = threadIdx.x;
    const int wave = tid >> 6;
    const int lane = tid & 63;
    const int l32  = lane & 31;
    const bool hi  = lane >= 32;
    const int row  = blockIdx.x * WPB + wave;

// uniform float extract: v_readlane (index SGPR-uniform or inline const)
#define RLF(SRC, IDX) __uint_as_float(__builtin_amdgcn_readlane(__float_as_uint(SRC), (IDX)))

    if (row < total_rows) {
        // ---- per-wave staging: own row only (coalesced float4) ----
        {
            const float4* s4 = (const float4*)(y + (size_t)row * TVW);
            float4* b4 = (float4*)(buf + wave * TVW);
            #pragma unroll
            for (int i = 0; i < TVW / 4; i += 64)
                b4[i + lane] = s4[i + lane];
        }

        const int c = (row / TVH) % TVC;
        float lam = log1pf(expf(lmbd[c]));   // softplus, once per row
        lam = __uint_as_float(__builtin_amdgcn_readfirstlane(__float_as_uint(lam)));
        const float nlam   = -lam;
        const float twolam = 2.0f * lam;
        float* x = buf + wave * TVW;         // row; prefix [..k0) never re-read

        const float sgn   = hi ? -1.0f : 1.0f;     // hi runs the mirrored walk
        const float vnlam = -lam;                  // fma addend
        const float vmcn  = hi ? -twolam : -0.0f;  // -(cneg): neg-jump restart
        const float vmcp  = hi ? -0.0f : -twolam;  // -(cpos): pos-jump restart
        const float laneF = (float)lane;
        const float rwc   = __builtin_amdgcn_rcpf(laneF + 1.0f);  // rcp(lane+1)

        // All cross-label state declared up-front (goto-safe).
        int k0, wb, dw2, j, jm, jend, rd, kmv, kcv, seg_guard;
        unsigned long long jb;
        float u, v, nvs, wv, tt, rdf, ywin, ywin2;
        bool negj;

        // Packed walk state: lo lanes = (umin,vmin); hi lanes = (-umax,-vmax).
        // Windows: ywin = x[wb..wb+63], ywin2 = x[wb+dw2..wb+dw2+63], dw2=56.
        k0 = 0; wb = 0; dw2 = 56; seg_guard = 6144; jb = 0;
        ywin  = x[lane];
        ywin2 = x[56 + lane];
        nvs = RLF(ywin, 0);              // x[0]
        v = fmaf(sgn, nvs, vnlam);       // lo: y0-lam ; hi: -(y0+lam)
        u = lam;
        kmv = 0; kcv = 1;
        j = 1; rd = 1;                   // j = pos - wb ; rd = pos - k0 (den-1)
        jend = TVW - 1 - wb;             // j of last absorbable element (511)

// absorb one element: SY = uniform raw y, SR = 1/den
#define TVSTEP(SY, SR) { \
            const float u_t = fmaf(sgn, (SY), u) - v; \
            jb = __ballot(u_t < nlam);   /* lo: umin_t<-lam, hi: umax_t>lam */ \
            if (jb) goto midjump; \
            kmv = (u_t >= lam) ? kcv : kmv;  /* v_cmp + v_cndmask */ \
            kcv += 1; \
            const float u_n = fminf(u_t, lam); \
            v = fmaf(u_t - u_n, (SR), v);    /* both clamp corrections */ \
            u = u_n; }

loopA:  // hot loop: j <= 63 (=> rd <= j <= 63, rwc valid)
        jm = jend < 63 ? jend : 63;
        while (j <= jm) {
            TVSTEP(RLF(ywin, j), RLF(rwc, rd))
            j += 1; rd += 1;
        }
        if (j > jend) goto boundary;
        // ---- loop B: j in [64, jend]; ywin2 with own sliding base ----
        rdf = (float)(rd + 1);           // den as float
        while (j <= jend) {
            if (j - dw2 >= 64) {         // slide ywin2 (amortized 1/56 absorbs)
                dw2 += 56;
                ywin2 = x[wb + dw2 + lane];
            }
            TVSTEP(RLF(ywin2, j - dw2), __builtin_amdgcn_rcpf(rdf))
            j += 1; rd += 1; rdf += 1.0f;
        }

boundary: // k == W-1 absorbed; u = umin (lo) / -umax (hi)
        {
            const unsigned long long bb = __ballot(u < 0.0f); // lo: umin<0, hi: umax>0
            if ((unsigned)bb) {              // flush [k0..km] at vmin; keep vmax/kp
                const int fe = __builtin_amdgcn_readlane(kmv, 0);   // km
                const int k0n = fe + 1;
                wv = v;                      // lo lanes hold vmin natively
                { const int pe = fe < TVW - 1 ? fe : TVW - 1;
                  if (!hi) for (int p = k0 + l32; p <= pe; p += 32) x[p] = wv; }
                if (k0n >= TVW) goto done;
                if (dw2 != 56) { ywin2 = x[wb + 56 + lane]; dw2 = 56; }
                while (k0n - wb >= 56) {     // persistent-window slide
                    wb += 56;
                    ywin = ywin2;
                    ywin2 = x[wb + 56 + lane];
                }
                nvs = RLF(ywin, k0n - wb);   // register-only restart value
                tt = fmaf(sgn, nvs, vnlam);  // hi: -x[k0n]-lam (lo value unused)
                u = hi ? (tt - v) : lam;     // uses OLD v (V_old)
                v = hi ? v : nvs;
                kmv = hi ? kmv : k0n;        // reset km (lo) only; kp kept
                kcv = k0n + 1;
                k0 = k0n;
                j = k0n - wb + 1; rd = 1; jend = TVW - 1 - wb;
                if (--seg_guard < 0) goto done;
                goto loopA;
            } else if ((unsigned)(bb >> 32)) { // flush [k0..kp] at vmax; keep vmin/km
                const int fe = __builtin_amdgcn_readlane(kmv, 32);  // kp
                const int k0n = fe + 1;
                wv = -v;                     // hi lanes hold -vmax natively
                { const int pe = fe < TVW - 1 ? fe : TVW - 1;
                  if (hi) for (int p = k0 + l32; p <= pe; p += 32) x[p] = wv; }
                if (k0n >= TVW) goto done;
                if (dw2 != 56) { ywin2 = x[wb + 56 + lane]; dw2 = 56; }
                while (k0n - wb >= 56) {
                    wb += 56;
                    ywin = ywin2;
                    ywin2 = x[wb + 56 + lane];
                }
                nvs = RLF(ywin, k0n - wb);
                tt = nvs + vnlam;            // lo: x[k0n]-lam (hi value unused)
                u = hi ? lam : (tt - v);     // uses OLD v (vmin)
                v = hi ? (-nvs) : v;
                kmv = hi ? k0n : kmv;        // reset kp (hi) only; km kept
                kcv = k0n + 1;
                k0 = k0n;
                j = k0n - wb + 1; rd = 1; jend = TVW - 1 - wb;
                if (--seg_guard < 0) goto done;
                goto loopA;
            } else {                         // terminate: flush tail at mean value
                const float vt = fmaf(u, __builtin_amdgcn_rcpf((float)(TVW - k0)), v);
                if (!hi) for (int p = k0 + l32; p < TVW; p += 32) x[p] = vt;
                goto done;
            }
        }

midjump: // jump while absorbing; jb lo bits = negative (priority), hi = positive
        {
            negj = (unsigned)jb != 0;
            const int fe = __builtin_amdgcn_readlane(kmv, negj ? 0 : 32); // km or kp
            const int k0n = fe + 1;          // fe <= W-2 here
            wv = hi ? -v : v;                // value this half would write
            {
                const int p0 = k0 + l32;
                if ((negj != hi) && (p0 <= fe)) x[p0] = wv;   // common case: 1 store
                if (fe - k0 >= 32) {                          // rare long segment
                    if (negj != hi)
                        for (int p = p0 + 32; p <= fe; p += 32) x[p] = wv;
                }
            }
            if (dw2 != 56) { ywin2 = x[wb + 56 + lane]; dw2 = 56; }
            while (k0n - wb >= 56) {         // persistent-window slide
                wb += 56;
                ywin = ywin2;
                ywin2 = x[wb + 56 + lane];
            }
            nvs = RLF(ywin, k0n - wb);       // register-only restart value
            v = fmaf(sgn, nvs, negj ? vmcn : vmcp);  // restart algebra, sign-folded
            u = lam;
            kmv = k0n; kcv = k0n + 1;
            k0 = k0n;
            j = k0n - wb + 1; rd = 1; jend = TVW - 1 - wb;
            if (--seg_guard < 0) goto done;
            goto loopA;
        }
#undef TVSTEP
done:   ;
        // ---- per-wave coalesced float4 writeback LDS -> out ----
        {
            const float4* b4 = (const float4*)(buf + wave * TVW);
            float4* d4 = (float4*)(out + (size_t)row * TVW);
            #pragma unroll
            for (int i = 0; i < TVW / 4; i += 64)
                d4[i + lane] = b4[i + lane];
        }
    }
#undef RLF
}

extern "C" void kernel_launch(void* const* d_in, const int* in_sizes, int n_in,
                              void* d_out, int out_size, void* d_ws, size_t ws_size,
                              hipStream_t stream) {
    const float* y    = (const float*)d_in[0];
    const float* lmbd = (const float*)d_in[1];
    float* out = (float*)d_out;

    const int total_rows = in_sizes[0] / TVW;              // 6144
    const int grid = (total_rows + WPB - 1) / WPB;         // 3072 blocks
    tv1d_condat_wave_kernel<<<grid, BLOCK, 0, stream>>>(y, lmbd, out, total_rows);
}